// Round 1
// baseline (1537.104 us; speedup 1.0000x reference)
//
#include <hip/hip_runtime.h>
#include <hip/hip_bf16.h>
#include <math.h>

#define H 768
#define G3 2304   // 3*H
#define E 256
#define NB 2048   // batch
#define DD 16

typedef __attribute__((ext_vector_type(8))) short bf16x8;
typedef __attribute__((ext_vector_type(4))) float f32x4;

__device__ __forceinline__ void gload_lds16(const void* g, void* lds) {
  __builtin_amdgcn_global_load_lds((const __attribute__((address_space(1))) void*)g,
                                   (__attribute__((address_space(3))) void*)lds, 16, 0, 0);
}

// ---------- f32 -> bf16 conversion ----------
__global__ void k_f2b(const float* __restrict__ in, __hip_bfloat16* __restrict__ out, int n) {
  int i = blockIdx.x * 256 + threadIdx.x;
  if (i < n) out[i] = __float2bfloat16(in[i]);
}

// ---------- encoder velocity embedding: all 7 frames ----------
__global__ void k_embed_enc(const float* __restrict__ obs,
                            const float* __restrict__ emb_W,
                            const float* __restrict__ emb_b,
                            __hip_bfloat16* __restrict__ out) {
  __shared__ float v[DD];
  int r = blockIdx.x;            // 0..7*2048-1 ; s = r>>11, n = r&2047
  int s = r >> 11, n = r & 2047;
  int t = threadIdx.x;           // e index, 0..255
  if (t < DD) {
    v[t] = obs[((size_t)(s + 1) * NB + n) * DD + t] - obs[((size_t)s * NB + n) * DD + t];
  }
  __syncthreads();
  float sum = 0.f;
#pragma unroll
  for (int d = 0; d < DD; ++d) sum += v[d] * emb_W[t * DD + d];
  out[(size_t)r * E + t] = __float2bfloat16(4.0f * sum + emb_b[t]);
}

// ---------- decoder velocity embedding (one frame) ----------
__global__ void k_embed_dec(const float* __restrict__ o1,
                            const float* __restrict__ o2,
                            const float* __restrict__ emb_W,
                            const float* __restrict__ emb_b,
                            __hip_bfloat16* __restrict__ out) {
  __shared__ float v[DD];
  int n = blockIdx.x;
  int t = threadIdx.x;
  if (t < DD) v[t] = o2[(size_t)n * DD + t] - o1[(size_t)n * DD + t];
  __syncthreads();
  float sum = 0.f;
#pragma unroll
  for (int d = 0; d < DD; ++d) sum += v[d] * emb_W[t * DD + d];
  out[(size_t)n * E + t] = __float2bfloat16(4.0f * sum + emb_b[t]);
}

// ---------- bf16 GEMM: C[M=2048][N=2304] = A(M x K, lda) @ B(N x ldb rows, take K cols)^T + bias ----------
__global__ __launch_bounds__(256) void k_gemm(
    const __hip_bfloat16* __restrict__ A, int lda,
    const __hip_bfloat16* __restrict__ B, int ldb,
    const float* __restrict__ bias,
    float* __restrict__ C, int ldc, int K) {
  __shared__ __align__(16) __hip_bfloat16 Asm[128 * 32];
  __shared__ __align__(16) __hip_bfloat16 Bsm[128 * 32];
  const int tid = threadIdx.x;
  const int w = tid >> 6, l = tid & 63;
  const int bm = blockIdx.y, bn = blockIdx.x;
  const int wm = w >> 1, wn = w & 1;
  const int lr = l & 15, lk = l >> 4;

  f32x4 acc[4][4];
#pragma unroll
  for (int m = 0; m < 4; ++m)
#pragma unroll
    for (int n = 0; n < 4; ++n) acc[m][n] = (f32x4){0.f, 0.f, 0.f, 0.f};

  const int rowA = bm * 128, rowB = bn * 128;

  for (int kb = 0; kb < K; kb += 32) {
#pragma unroll
    for (int i = 0; i < 2; ++i) {
      int off = i * 4096 + w * 1024 + l * 16;  // byte offset in 8192-byte tile
      int r = off >> 6;                        // 64 B per row (32 bf16)
      int kk = (off & 63) >> 1;                // element within row
      gload_lds16(A + (size_t)(rowA + r) * lda + kb + kk, (char*)Asm + i * 4096 + w * 1024);
      gload_lds16(B + (size_t)(rowB + r) * ldb + kb + kk, (char*)Bsm + i * 4096 + w * 1024);
    }
    __syncthreads();
    bf16x8 af[4], bfr[4];
#pragma unroll
    for (int m = 0; m < 4; ++m)
      af[m] = *(const bf16x8*)(Asm + (wm * 64 + m * 16 + lr) * 32 + lk * 8);
#pragma unroll
    for (int n = 0; n < 4; ++n)
      bfr[n] = *(const bf16x8*)(Bsm + (wn * 64 + n * 16 + lr) * 32 + lk * 8);
#pragma unroll
    for (int m = 0; m < 4; ++m)
#pragma unroll
      for (int n = 0; n < 4; ++n)
        acc[m][n] = __builtin_amdgcn_mfma_f32_16x16x32_bf16(af[m], bfr[n], acc[m][n], 0, 0, 0);
    __syncthreads();
  }

#pragma unroll
  for (int m = 0; m < 4; ++m) {
#pragma unroll
    for (int n = 0; n < 4; ++n) {
      int col = bn * 128 + wn * 64 + n * 16 + lr;
      float bv = bias ? bias[col] : 0.f;
#pragma unroll
      for (int r4 = 0; r4 < 4; ++r4) {
        int row = bm * 128 + wm * 64 + m * 16 + lk * 4 + r4;
        C[(size_t)row * ldc + col] = acc[m][n][r4] + bv;
      }
    }
  }
}

// ---------- GRU gate update ----------
__global__ void k_gru(const float* __restrict__ gi,
                      const float* __restrict__ gi2,  // nullable extra addend (e2 h_inv part)
                      const float* __restrict__ gh,   // nullable -> use bhh only (h==0 step)
                      const float* __restrict__ bhh,
                      const float* __restrict__ h_in, // nullable -> 0
                      float* __restrict__ h_out,
                      __hip_bfloat16* __restrict__ hb_out) {
  int idx = blockIdx.x * 256 + threadIdx.x;  // < 2048*768
  int row = idx / H, j = idx - row * H;
  size_t b = (size_t)row * G3 + j;
  float ir = gi[b], iz = gi[b + H], in_ = gi[b + 2 * H];
  if (gi2) { ir += gi2[b]; iz += gi2[b + H]; in_ += gi2[b + 2 * H]; }
  float hr, hz, hn;
  if (gh) { hr = gh[b]; hz = gh[b + H]; hn = gh[b + 2 * H]; }
  else    { hr = bhh[j]; hz = bhh[j + H]; hn = bhh[j + 2 * H]; }
  float r = 1.f / (1.f + expf(-(ir + hr)));
  float z = 1.f / (1.f + expf(-(iz + hz)));
  float nn = tanhf(in_ + r * hn);
  float h0 = h_in ? h_in[idx] : 0.f;
  float h = (1.f - z) * nn + z * h0;
  h_out[idx] = h;
  hb_out[idx] = __float2bfloat16(h);
}

// ---------- decoder head: h2n + mix + pos ----------
__global__ void k_head(const float* __restrict__ h,
                       const float* __restrict__ obs2,
                       const float* __restrict__ h2n_W,
                       const float* __restrict__ h2n_b,
                       const float* __restrict__ mix_W,
                       const float* __restrict__ mix_b,
                       float* __restrict__ rel_out,
                       float* __restrict__ pos_out) {
  int wv = threadIdx.x >> 6, lane = threadIdx.x & 63;
  int row = blockIdx.x * 4 + wv;
  float s0 = 0.f, s1 = 0.f, s2 = 0.f, s3 = 0.f, s4 = 0.f;
  for (int k = lane; k < H; k += 64) {
    float hv = h[(size_t)row * H + k];
    s0 += hv * h2n_W[0 * H + k];
    s1 += hv * h2n_W[1 * H + k];
    s2 += hv * h2n_W[2 * H + k];
    s3 += hv * h2n_W[3 * H + k];
    s4 += hv * h2n_W[4 * H + k];
  }
#pragma unroll
  for (int off = 32; off; off >>= 1) {
    s0 += __shfl_down(s0, off);
    s1 += __shfl_down(s1, off);
    s2 += __shfl_down(s2, off);
    s3 += __shfl_down(s3, off);
    s4 += __shfl_down(s4, off);
  }
  if (lane == 0) {
    float nv[5];
    nv[0] = s0 + h2n_b[0];
    nv[1] = s1 + h2n_b[1];
    float x2 = s2 + h2n_b[2], x3 = s3 + h2n_b[3];
    nv[2] = 0.01f + 0.2f * (x2 > 0.f ? x2 + log1pf(expf(-x2)) : log1pf(expf(x2)));
    nv[3] = 0.01f + 0.2f * (x3 > 0.f ? x3 + log1pf(expf(-x3)) : log1pf(expf(x3)));
    float x4 = s4 + h2n_b[4];
    nv[4] = 0.7f * tanhf(x4);
#pragma unroll
    for (int c = 0; c < 5; ++c) rel_out[(size_t)row * 5 + c] = nv[c];
#pragma unroll
    for (int d = 0; d < DD; ++d) {
      float a = mix_b[d];
#pragma unroll
      for (int c = 0; c < 5; ++c) a += nv[c] * mix_W[d * 5 + c];
      float rl = a > 0.f ? a : 0.f;
      pos_out[(size_t)row * DD + d] = obs2[(size_t)row * DD + d] + rl;
    }
  }
}

extern "C" void kernel_launch(void* const* d_in, const int* in_sizes, int n_in,
                              void* d_out, int out_size, void* d_ws, size_t ws_size,
                              hipStream_t stream) {
  (void)in_sizes; (void)n_in; (void)out_size; (void)ws_size;
  const float* observed = (const float*)d_in[0];
  const float* emb_W   = (const float*)d_in[1];
  const float* emb_b   = (const float*)d_in[2];
  const float* e1_Wih  = (const float*)d_in[3];
  const float* e1_Whh  = (const float*)d_in[4];
  const float* e1_bih  = (const float*)d_in[5];
  const float* e1_bhh  = (const float*)d_in[6];
  const float* e2_Wih  = (const float*)d_in[7];
  const float* e2_Whh  = (const float*)d_in[8];
  const float* e2_bih  = (const float*)d_in[9];
  const float* e2_bhh  = (const float*)d_in[10];
  const float* dec_Wih = (const float*)d_in[11];
  const float* dec_Whh = (const float*)d_in[12];
  const float* dec_bih = (const float*)d_in[13];
  const float* dec_bhh = (const float*)d_in[14];
  const float* h2n_W   = (const float*)d_in[15];
  const float* h2n_b   = (const float*)d_in[16];
  const float* mix_W   = (const float*)d_in[17];
  const float* mix_b   = (const float*)d_in[18];

  char* p = (char*)d_ws;
  auto alloc = [&](size_t bytes) { char* r = p; p += (bytes + 255) & ~(size_t)255; return r; };

  __hip_bfloat16* Ev  = (__hip_bfloat16*)alloc((size_t)7 * NB * E * 2);
  __hip_bfloat16* Ed  = (__hip_bfloat16*)alloc((size_t)NB * E * 2);
  float*          hf  = (float*)alloc((size_t)NB * H * 4);
  __hip_bfloat16* hb  = (__hip_bfloat16*)alloc((size_t)NB * H * 2);
  float*          gi  = (float*)alloc((size_t)NB * G3 * 4);
  float*          gh  = (float*)alloc((size_t)NB * G3 * 4);
  float*          g2h = (float*)alloc((size_t)NB * G3 * 4);
  __hip_bfloat16* b_e1_Wih  = (__hip_bfloat16*)alloc((size_t)G3 * E * 2);
  __hip_bfloat16* b_e1_Whh  = (__hip_bfloat16*)alloc((size_t)G3 * H * 2);
  __hip_bfloat16* b_e2_Wih  = (__hip_bfloat16*)alloc((size_t)G3 * (E + H) * 2);
  __hip_bfloat16* b_e2_Whh  = (__hip_bfloat16*)alloc((size_t)G3 * H * 2);
  __hip_bfloat16* b_dec_Wih = (__hip_bfloat16*)alloc((size_t)G3 * E * 2);
  __hip_bfloat16* b_dec_Whh = (__hip_bfloat16*)alloc((size_t)G3 * H * 2);

  auto conv = [&](const float* s, __hip_bfloat16* dst, int n) {
    k_f2b<<<(n + 255) / 256, 256, 0, stream>>>(s, dst, n);
  };
  conv(e1_Wih, b_e1_Wih, G3 * E);
  conv(e1_Whh, b_e1_Whh, G3 * H);
  conv(e2_Wih, b_e2_Wih, G3 * (E + H));
  conv(e2_Whh, b_e2_Whh, G3 * H);
  conv(dec_Wih, b_dec_Wih, G3 * E);
  conv(dec_Whh, b_dec_Whh, G3 * H);

  k_embed_enc<<<7 * NB, 256, 0, stream>>>(observed, emb_W, emb_b, Ev);

  dim3 gemmGrid(G3 / 128, NB / 128);  // (18,16)
  auto gemm = [&](const __hip_bfloat16* A, int lda, const __hip_bfloat16* B, int ldb,
                  const float* bias, float* C, int K) {
    k_gemm<<<gemmGrid, 256, 0, stream>>>(A, lda, B, ldb, bias, C, G3, K);
  };

  // ---- encoder 1 (runs velocities back-to-front: frame 6-t) ----
  for (int t = 0; t < 7; ++t) {
    const __hip_bfloat16* x = Ev + (size_t)(6 - t) * NB * E;
    gemm(x, E, b_e1_Wih, E, e1_bih, gi, E);
    if (t > 0) gemm(hb, H, b_e1_Whh, H, e1_bhh, gh, H);
    k_gru<<<NB * H / 256, 256, 0, stream>>>(gi, nullptr, t > 0 ? gh : nullptr, e1_bhh,
                                            t > 0 ? hf : nullptr, hf, hb);
  }
  // ---- e2 constant part: h_inv @ e2_Wih[:, E:]^T (no bias) ----
  gemm(hb, H, b_e2_Wih + E, E + H, nullptr, g2h, H);
  // ---- encoder 2 (front-to-back) ----
  for (int t = 0; t < 7; ++t) {
    const __hip_bfloat16* x = Ev + (size_t)t * NB * E;
    gemm(x, E, b_e2_Wih, E + H, e2_bih, gi, E);
    if (t > 0) gemm(hb, H, b_e2_Whh, H, e2_bhh, gh, H);
    k_gru<<<NB * H / 256, 256, 0, stream>>>(gi, g2h, t > 0 ? gh : nullptr, e2_bhh,
                                            t > 0 ? hf : nullptr, hf, hb);
  }
  // ---- decoder ----
  float* rel  = (float*)d_out;                    // (12, 2048, 5)
  float* pred = (float*)d_out + (size_t)12 * NB * 5;  // (12, 2048, 16)
  for (int k = 0; k < 12; ++k) {
    const float *o1, *o2;
    if (k == 0)      { o1 = observed + (size_t)6 * NB * DD; o2 = observed + (size_t)7 * NB * DD; }
    else if (k == 1) { o1 = observed + (size_t)7 * NB * DD; o2 = pred; }
    else             { o1 = pred + (size_t)(k - 2) * NB * DD; o2 = pred + (size_t)(k - 1) * NB * DD; }
    k_embed_dec<<<NB, 256, 0, stream>>>(o1, o2, emb_W, emb_b, Ed);
    gemm(Ed, E, b_dec_Wih, E, dec_bih, gi, E);
    gemm(hb, H, b_dec_Whh, H, dec_bhh, gh, H);
    k_gru<<<NB * H / 256, 256, 0, stream>>>(gi, nullptr, gh, dec_bhh, hf, hf, hb);
    k_head<<<NB / 4, 256, 0, stream>>>(hf, o2, h2n_W, h2n_b, mix_W, mix_b,
                                       rel + (size_t)k * NB * 5, pred + (size_t)k * NB * DD);
  }
}

// Round 2
// 1390.860 us; speedup vs baseline: 1.1051x; 1.1051x over previous
//
#include <hip/hip_runtime.h>
#include <hip/hip_bf16.h>
#include <math.h>

#define H 768
#define G3 2304   // 3*H
#define E 256
#define NB 2048
#define DD 16

typedef __attribute__((ext_vector_type(8))) short bf16x8;
typedef __attribute__((ext_vector_type(4))) float f32x4;

__device__ __forceinline__ void gload_lds16(const void* g, void* lds) {
  __builtin_amdgcn_global_load_lds((const __attribute__((address_space(1))) void*)g,
                                   (__attribute__((address_space(3))) void*)lds, 16, 0, 0);
}

__device__ __forceinline__ float b2f(short s) {
  union { unsigned int u; float f; } c;
  c.u = ((unsigned int)(unsigned short)s) << 16;
  return c.f;
}

// ---------- plain f32 -> bf16 ----------
__global__ void k_f2b(const float* __restrict__ in, __hip_bfloat16* __restrict__ out, int n) {
  int i = blockIdx.x * 256 + threadIdx.x;
  if (i < n) out[i] = __float2bfloat16(in[i]);
}

// ---------- pack [Wih_rz | Whh_rz] -> 1536 x 1024 bf16 ----------
__global__ void k_pack_rz(const float* __restrict__ Wih, int ldih,
                          const float* __restrict__ Whh, __hip_bfloat16* __restrict__ dst) {
  int idx = blockIdx.x * 256 + threadIdx.x;  // < 1536*1024
  int r = idx >> 10, c = idx & 1023;
  float v = (c < 256) ? Wih[(size_t)r * ldih + c] : Whh[(size_t)r * H + c - 256];
  dst[idx] = __float2bfloat16(v);
}

// ---------- pack Wih_n x-part -> 768 x 256 bf16 (handles strided e2) ----------
__global__ void k_pack_in(const float* __restrict__ Wih, int ldih, __hip_bfloat16* __restrict__ dst) {
  int idx = blockIdx.x * 256 + threadIdx.x;  // < 768*256
  int r = idx >> 8, c = idx & 255;
  dst[idx] = __float2bfloat16(Wih[(size_t)(1536 + r) * ldih + c]);
}

// ---------- pack e2_Wih[:, 256:] -> 2304 x 768 bf16 ----------
__global__ void k_pack_g(const float* __restrict__ Wih, __hip_bfloat16* __restrict__ dst) {
  int idx = blockIdx.x * 256 + threadIdx.x;  // < 2304*768
  int r = idx / H, c = idx - r * H;
  dst[idx] = __float2bfloat16(Wih[(size_t)r * 1024 + 256 + c]);
}

// ---------- build 3072-wide bias vectors: [bih+bhh (rz), bih_n, bhh_n] ----------
__global__ void k_bias(const float* b0i, const float* b0h, const float* b1i, const float* b1h,
                       const float* b2i, const float* b2h,
                       float* d0, float* d1, float* d2) {
  int idx = blockIdx.x * 256 + threadIdx.x;  // < 3*3072
  int s = idx / 3072, c = idx - s * 3072;
  const float* bih = s == 0 ? b0i : s == 1 ? b1i : b2i;
  const float* bhh = s == 0 ? b0h : s == 1 ? b1h : b2h;
  float v;
  if (c < 1536) v = bih[c] + bhh[c];
  else if (c < 2304) v = bih[c];
  else v = bhh[c - 768];
  (s == 0 ? d0 : s == 1 ? d1 : d2)[c] = v;
}

// ---------- encoder velocity embeddings, 7 frames ----------
__global__ void k_embed_enc(const float* __restrict__ obs,
                            const float* __restrict__ emb_W,
                            const float* __restrict__ emb_b,
                            __hip_bfloat16* __restrict__ Ev) {
  __shared__ float v[DD];
  int r = blockIdx.x;  // s = r>>11, n = r&2047
  int s = r >> 11, n = r & 2047;
  int t = threadIdx.x;
  if (t < DD)
    v[t] = obs[((size_t)(s + 1) * NB + n) * DD + t] - obs[((size_t)s * NB + n) * DD + t];
  __syncthreads();
  float sum = 0.f;
#pragma unroll
  for (int d = 0; d < DD; ++d) sum += v[d] * emb_W[t * DD + d];
  Ev[(size_t)r * E + t] = __float2bfloat16(4.0f * sum + emb_b[t]);
}

// ---------- decoder embedding, step 0 only ----------
__global__ void k_embed_dec(const float* __restrict__ o1, const float* __restrict__ o2,
                            const float* __restrict__ emb_W, const float* __restrict__ emb_b,
                            __hip_bfloat16* __restrict__ out) {
  __shared__ float v[DD];
  int n = blockIdx.x;
  int t = threadIdx.x;
  if (t < DD) v[t] = o2[(size_t)n * DD + t] - o1[(size_t)n * DD + t];
  __syncthreads();
  float sum = 0.f;
#pragma unroll
  for (int d = 0; d < DD; ++d) sum += v[d] * emb_W[t * DD + d];
  out[(size_t)n * E + t] = __float2bfloat16(4.0f * sum + emb_b[t]);
}

// ---------- gate GEMM: one launch computes all GRU pre-activations ----------
// out cols: [0,1536)=r,z over K=1024 ([A1|A2]); [1536,2304)=in_ over K=256 (A1);
//           [2304,3072)=hn over K=768 (A2).  G[row][col] bf16, +bias, +add(e2: g2h).
__global__ __launch_bounds__(256) void k_gates(
    const __hip_bfloat16* __restrict__ A1,   // 2048 x 256  (embed)
    const __hip_bfloat16* __restrict__ A2,   // 2048 x 768  (h bf16)
    const __hip_bfloat16* __restrict__ Brz,  // 1536 x 1024
    const __hip_bfloat16* __restrict__ Bin,  // 768 x 256
    const __hip_bfloat16* __restrict__ Bhn,  // 768 x 768
    const float* __restrict__ bias,          // 3072
    const __hip_bfloat16* __restrict__ add,  // 2048 x 2304 or null
    __hip_bfloat16* __restrict__ Gout) {     // 2048 x 3072
  __shared__ __align__(16) __hip_bfloat16 Asm[128 * 32];
  __shared__ __align__(16) __hip_bfloat16 Bsm[128 * 32];
  const int tid = threadIdx.x;
  const int w = tid >> 6, l = tid & 63;
  const int bm = blockIdx.y, bn = blockIdx.x;
  const int wm = w >> 1, wn = w & 1;
  const int lr = l & 15, lk = l >> 4;

  const __hip_bfloat16* B;
  int ldb, brow, kbeg, kend, kboff;
  if (bn < 12)      { B = Brz; ldb = 1024; brow = bn * 128;        kbeg = 0;   kend = 1024; kboff = 0; }
  else if (bn < 18) { B = Bin; ldb = 256;  brow = (bn - 12) * 128; kbeg = 0;   kend = 256;  kboff = 0; }
  else              { B = Bhn; ldb = 768;  brow = (bn - 18) * 128; kbeg = 256; kend = 1024; kboff = 256; }

  f32x4 acc[4][4];
#pragma unroll
  for (int m = 0; m < 4; ++m)
#pragma unroll
    for (int n = 0; n < 4; ++n) acc[m][n] = (f32x4){0.f, 0.f, 0.f, 0.f};

  const int rowA = bm * 128;
  const int off0 = w * 1024 + l * 16;

  for (int kb = kbeg; kb < kend; kb += 32) {
    const __hip_bfloat16* Ab;
    int lda, ac;
    if (kb < 256) { Ab = A1; lda = 256; ac = kb; }
    else          { Ab = A2; lda = 768; ac = kb - 256; }
    const int bc = kb - kboff;
#pragma unroll
    for (int i = 0; i < 2; ++i) {
      int o = i * 4096 + off0;
      int r = o >> 6, kk = (o & 63) >> 1;
      gload_lds16(Ab + (size_t)(rowA + r) * lda + ac + kk, (char*)Asm + i * 4096 + w * 1024);
      gload_lds16(B + (size_t)(brow + r) * ldb + bc + kk, (char*)Bsm + i * 4096 + w * 1024);
    }
    __syncthreads();
    bf16x8 af[4], bfr[4];
#pragma unroll
    for (int m = 0; m < 4; ++m)
      af[m] = *(const bf16x8*)(Asm + (wm * 64 + m * 16 + lr) * 32 + lk * 8);
#pragma unroll
    for (int n = 0; n < 4; ++n)
      bfr[n] = *(const bf16x8*)(Bsm + (wn * 64 + n * 16 + lr) * 32 + lk * 8);
#pragma unroll
    for (int m = 0; m < 4; ++m)
#pragma unroll
      for (int n = 0; n < 4; ++n)
        acc[m][n] = __builtin_amdgcn_mfma_f32_16x16x32_bf16(af[m], bfr[n], acc[m][n], 0, 0, 0);
    __syncthreads();
  }

#pragma unroll
  for (int m = 0; m < 4; ++m) {
#pragma unroll
    for (int n = 0; n < 4; ++n) {
      int col = bn * 128 + wn * 64 + n * 16 + lr;
      float bv = bias[col];
#pragma unroll
      for (int r4 = 0; r4 < 4; ++r4) {
        int row = rowA + wm * 64 + m * 16 + lk * 4 + r4;
        float v = acc[m][n][r4] + bv;
        if (add && col < 2304) v += b2f(((const short*)add)[(size_t)row * 2304 + col]);
        Gout[(size_t)row * 3072 + col] = __float2bfloat16(v);
      }
    }
  }
}

// ---------- plain GEMM (for g2h): C[2048][2304] = A(2048x768) @ B(2304x768)^T, bf16 out ----------
__global__ __launch_bounds__(256) void k_plain(
    const __hip_bfloat16* __restrict__ A,
    const __hip_bfloat16* __restrict__ B,
    __hip_bfloat16* __restrict__ C) {
  __shared__ __align__(16) __hip_bfloat16 Asm[128 * 32];
  __shared__ __align__(16) __hip_bfloat16 Bsm[128 * 32];
  const int tid = threadIdx.x;
  const int w = tid >> 6, l = tid & 63;
  const int bm = blockIdx.y, bn = blockIdx.x;
  const int wm = w >> 1, wn = w & 1;
  const int lr = l & 15, lk = l >> 4;

  f32x4 acc[4][4];
#pragma unroll
  for (int m = 0; m < 4; ++m)
#pragma unroll
    for (int n = 0; n < 4; ++n) acc[m][n] = (f32x4){0.f, 0.f, 0.f, 0.f};

  const int rowA = bm * 128, rowB = bn * 128;
  const int off0 = w * 1024 + l * 16;

  for (int kb = 0; kb < H; kb += 32) {
#pragma unroll
    for (int i = 0; i < 2; ++i) {
      int o = i * 4096 + off0;
      int r = o >> 6, kk = (o & 63) >> 1;
      gload_lds16(A + (size_t)(rowA + r) * H + kb + kk, (char*)Asm + i * 4096 + w * 1024);
      gload_lds16(B + (size_t)(rowB + r) * H + kb + kk, (char*)Bsm + i * 4096 + w * 1024);
    }
    __syncthreads();
    bf16x8 af[4], bfr[4];
#pragma unroll
    for (int m = 0; m < 4; ++m)
      af[m] = *(const bf16x8*)(Asm + (wm * 64 + m * 16 + lr) * 32 + lk * 8);
#pragma unroll
    for (int n = 0; n < 4; ++n)
      bfr[n] = *(const bf16x8*)(Bsm + (wn * 64 + n * 16 + lr) * 32 + lk * 8);
#pragma unroll
    for (int m = 0; m < 4; ++m)
#pragma unroll
      for (int n = 0; n < 4; ++n)
        acc[m][n] = __builtin_amdgcn_mfma_f32_16x16x32_bf16(af[m], bfr[n], acc[m][n], 0, 0, 0);
    __syncthreads();
  }

#pragma unroll
  for (int m = 0; m < 4; ++m)
#pragma unroll
    for (int n = 0; n < 4; ++n) {
      int col = bn * 128 + wn * 64 + n * 16 + lr;
#pragma unroll
      for (int r4 = 0; r4 < 4; ++r4) {
        int row = rowA + wm * 64 + m * 16 + lk * 4 + r4;
        C[(size_t)row * G3 + col] = __float2bfloat16(acc[m][n][r4]);
      }
    }
}

// ---------- GRU elementwise: 8 units/thread ----------
__global__ void k_gru(const __hip_bfloat16* __restrict__ Gin,
                      const float* __restrict__ h_in,
                      float* __restrict__ h_out,
                      __hip_bfloat16* __restrict__ hb_out) {
  int idx = blockIdx.x * 256 + threadIdx.x;  // < 2048*96
  int row = idx / 96, jb = (idx - row * 96) * 8;
  size_t gb = (size_t)row * 3072 + jb;
  bf16x8 rv = *(const bf16x8*)(Gin + gb);
  bf16x8 zv = *(const bf16x8*)(Gin + gb + 768);
  bf16x8 iv = *(const bf16x8*)(Gin + gb + 1536);
  bf16x8 nv = *(const bf16x8*)(Gin + gb + 2304);
  const float4* hp = (const float4*)(h_in + (size_t)row * H + jb);
  float4 ha = hp[0], hc = hp[1];
  float hv[8] = {ha.x, ha.y, ha.z, ha.w, hc.x, hc.y, hc.z, hc.w};
  float out[8];
  union { bf16x8 v; __hip_bfloat16 h[8]; } ob;
#pragma unroll
  for (int e = 0; e < 8; ++e) {
    float r = 1.f / (1.f + expf(-b2f(rv[e])));
    float z = 1.f / (1.f + expf(-b2f(zv[e])));
    float n = tanhf(b2f(iv[e]) + r * b2f(nv[e]));
    float hn2 = (1.f - z) * n + z * hv[e];
    out[e] = hn2;
    ob.h[e] = __float2bfloat16(hn2);
  }
  float4* op = (float4*)(h_out + (size_t)row * H + jb);
  op[0] = make_float4(out[0], out[1], out[2], out[3]);
  op[1] = make_float4(out[4], out[5], out[6], out[7]);
  *(bf16x8*)(hb_out + (size_t)row * H + jb) = ob.v;
}

// ---------- decoder head: h2n + mix + pos + NEXT-STEP EMBED (vel == relu output) ----------
__global__ void k_head(const float* __restrict__ h,
                       const float* __restrict__ obs2,
                       const float* __restrict__ h2n_W, const float* __restrict__ h2n_b,
                       const float* __restrict__ mix_W, const float* __restrict__ mix_b,
                       const float* __restrict__ emb_W, const float* __restrict__ emb_b,
                       float* __restrict__ rel_out, float* __restrict__ pos_out,
                       __hip_bfloat16* __restrict__ emb_out) {
  __shared__ float rl_s[4][DD];
  int wv = threadIdx.x >> 6, lane = threadIdx.x & 63;
  int row = blockIdx.x * 4 + wv;
  float s0 = 0.f, s1 = 0.f, s2 = 0.f, s3 = 0.f, s4 = 0.f;
  for (int k = lane; k < H; k += 64) {
    float hval = h[(size_t)row * H + k];
    s0 += hval * h2n_W[k];
    s1 += hval * h2n_W[H + k];
    s2 += hval * h2n_W[2 * H + k];
    s3 += hval * h2n_W[3 * H + k];
    s4 += hval * h2n_W[4 * H + k];
  }
#pragma unroll
  for (int off = 32; off; off >>= 1) {
    s0 += __shfl_down(s0, off);
    s1 += __shfl_down(s1, off);
    s2 += __shfl_down(s2, off);
    s3 += __shfl_down(s3, off);
    s4 += __shfl_down(s4, off);
  }
  s0 = __shfl(s0, 0); s1 = __shfl(s1, 0); s2 = __shfl(s2, 0);
  s3 = __shfl(s3, 0); s4 = __shfl(s4, 0);
  float n0 = s0 + h2n_b[0], n1 = s1 + h2n_b[1];
  float x2 = s2 + h2n_b[2], x3 = s3 + h2n_b[3], x4 = s4 + h2n_b[4];
  float n2 = 0.01f + 0.2f * (x2 > 0.f ? x2 + log1pf(expf(-x2)) : log1pf(expf(x2)));
  float n3 = 0.01f + 0.2f * (x3 > 0.f ? x3 + log1pf(expf(-x3)) : log1pf(expf(x3)));
  float n4 = 0.7f * tanhf(x4);
  if (lane < DD) {
    float a = mix_b[lane] + n0 * mix_W[lane * 5 + 0] + n1 * mix_W[lane * 5 + 1] +
              n2 * mix_W[lane * 5 + 2] + n3 * mix_W[lane * 5 + 3] + n4 * mix_W[lane * 5 + 4];
    float rl = a > 0.f ? a : 0.f;
    rl_s[wv][lane] = rl;
    pos_out[(size_t)row * DD + lane] = obs2[(size_t)row * DD + lane] + rl;
  }
  if (lane == 0) {
    rel_out[(size_t)row * 5 + 0] = n0;
    rel_out[(size_t)row * 5 + 1] = n1;
    rel_out[(size_t)row * 5 + 2] = n2;
    rel_out[(size_t)row * 5 + 3] = n3;
    rel_out[(size_t)row * 5 + 4] = n4;
  }
  __syncthreads();
  for (int e = lane; e < E; e += 64) {
    float s = 0.f;
#pragma unroll
    for (int d = 0; d < DD; ++d) s += rl_s[wv][d] * emb_W[e * DD + d];
    emb_out[(size_t)row * E + e] = __float2bfloat16(4.0f * s + emb_b[e]);
  }
}

extern "C" void kernel_launch(void* const* d_in, const int* in_sizes, int n_in,
                              void* d_out, int out_size, void* d_ws, size_t ws_size,
                              hipStream_t stream) {
  (void)in_sizes; (void)n_in; (void)out_size; (void)ws_size;
  const float* observed = (const float*)d_in[0];
  const float* emb_W   = (const float*)d_in[1];
  const float* emb_b   = (const float*)d_in[2];
  const float* e1_Wih  = (const float*)d_in[3];
  const float* e1_Whh  = (const float*)d_in[4];
  const float* e1_bih  = (const float*)d_in[5];
  const float* e1_bhh  = (const float*)d_in[6];
  const float* e2_Wih  = (const float*)d_in[7];
  const float* e2_Whh  = (const float*)d_in[8];
  const float* e2_bih  = (const float*)d_in[9];
  const float* e2_bhh  = (const float*)d_in[10];
  const float* dec_Wih = (const float*)d_in[11];
  const float* dec_Whh = (const float*)d_in[12];
  const float* dec_bih = (const float*)d_in[13];
  const float* dec_bhh = (const float*)d_in[14];
  const float* h2n_W   = (const float*)d_in[15];
  const float* h2n_b   = (const float*)d_in[16];
  const float* mix_W   = (const float*)d_in[17];
  const float* mix_b   = (const float*)d_in[18];

  char* p = (char*)d_ws;
  auto alloc = [&](size_t bytes) { char* r = p; p += (bytes + 255) & ~(size_t)255; return r; };

  __hip_bfloat16* Ev   = (__hip_bfloat16*)alloc((size_t)7 * NB * E * 2);
  __hip_bfloat16* Edec = (__hip_bfloat16*)alloc((size_t)NB * E * 2);
  __hip_bfloat16* hb1  = (__hip_bfloat16*)alloc((size_t)NB * H * 2);
  __hip_bfloat16* hb2  = (__hip_bfloat16*)alloc((size_t)NB * H * 2);
  float*          hf1  = (float*)alloc((size_t)NB * H * 4);
  float*          hf2  = (float*)alloc((size_t)NB * H * 4);
  __hip_bfloat16* Gb   = (__hip_bfloat16*)alloc((size_t)NB * 3072 * 2);
  __hip_bfloat16* g2h  = (__hip_bfloat16*)alloc((size_t)NB * G3 * 2);
  __hip_bfloat16* P1rz = (__hip_bfloat16*)alloc((size_t)1536 * 1024 * 2);
  __hip_bfloat16* P2rz = (__hip_bfloat16*)alloc((size_t)1536 * 1024 * 2);
  __hip_bfloat16* P3rz = (__hip_bfloat16*)alloc((size_t)1536 * 1024 * 2);
  __hip_bfloat16* P1in = (__hip_bfloat16*)alloc((size_t)768 * 256 * 2);
  __hip_bfloat16* P2in = (__hip_bfloat16*)alloc((size_t)768 * 256 * 2);
  __hip_bfloat16* P3in = (__hip_bfloat16*)alloc((size_t)768 * 256 * 2);
  __hip_bfloat16* P1hn = (__hip_bfloat16*)alloc((size_t)768 * 768 * 2);
  __hip_bfloat16* P2hn = (__hip_bfloat16*)alloc((size_t)768 * 768 * 2);
  __hip_bfloat16* P3hn = (__hip_bfloat16*)alloc((size_t)768 * 768 * 2);
  __hip_bfloat16* Bg   = (__hip_bfloat16*)alloc((size_t)G3 * H * 2);
  float* bias0 = (float*)alloc(3072 * 4);
  float* bias1 = (float*)alloc(3072 * 4);
  float* bias2 = (float*)alloc(3072 * 4);

  // ---- weight packing ----
  k_pack_rz<<<6144, 256, 0, stream>>>(e1_Wih, 256, e1_Whh, P1rz);
  k_pack_rz<<<6144, 256, 0, stream>>>(e2_Wih, 1024, e2_Whh, P2rz);
  k_pack_rz<<<6144, 256, 0, stream>>>(dec_Wih, 256, dec_Whh, P3rz);
  k_pack_in<<<768, 256, 0, stream>>>(e1_Wih, 256, P1in);
  k_pack_in<<<768, 256, 0, stream>>>(e2_Wih, 1024, P2in);
  k_pack_in<<<768, 256, 0, stream>>>(dec_Wih, 256, P3in);
  k_f2b<<<2304, 256, 0, stream>>>(e1_Whh + (size_t)1536 * H, P1hn, 768 * 768);
  k_f2b<<<2304, 256, 0, stream>>>(e2_Whh + (size_t)1536 * H, P2hn, 768 * 768);
  k_f2b<<<2304, 256, 0, stream>>>(dec_Whh + (size_t)1536 * H, P3hn, 768 * 768);
  k_pack_g<<<6912, 256, 0, stream>>>(e2_Wih, Bg);
  k_bias<<<36, 256, 0, stream>>>(e1_bih, e1_bhh, e2_bih, e2_bhh, dec_bih, dec_bhh,
                                 bias0, bias1, bias2);

  // ---- embeddings + zero states ----
  k_embed_enc<<<7 * NB, 256, 0, stream>>>(observed, emb_W, emb_b, Ev);
  k_embed_dec<<<NB, 256, 0, stream>>>(observed + (size_t)6 * NB * DD,
                                      observed + (size_t)7 * NB * DD, emb_W, emb_b, Edec);
  hipMemsetAsync(hb1, 0, (size_t)NB * H * 2, stream);
  hipMemsetAsync(hf1, 0, (size_t)NB * H * 4, stream);
  hipMemsetAsync(hb2, 0, (size_t)NB * H * 2, stream);
  hipMemsetAsync(hf2, 0, (size_t)NB * H * 4, stream);

  dim3 gg(24, 16);
  // ---- encoder 1 (velocity frames back-to-front) ----
  for (int t = 0; t < 7; ++t) {
    k_gates<<<gg, 256, 0, stream>>>(Ev + (size_t)(6 - t) * NB * E, hb1,
                                    P1rz, P1in, P1hn, bias0, nullptr, Gb);
    k_gru<<<768, 256, 0, stream>>>(Gb, hf1, hf1, hb1);
  }
  // ---- g2h = h_inv @ e2_Wih[:,256:]^T ----
  k_plain<<<dim3(18, 16), 256, 0, stream>>>(hb1, Bg, g2h);
  // ---- encoder 2 (front-to-back) ----
  for (int t = 0; t < 7; ++t) {
    k_gates<<<gg, 256, 0, stream>>>(Ev + (size_t)t * NB * E, hb2,
                                    P2rz, P2in, P2hn, bias1, g2h, Gb);
    k_gru<<<768, 256, 0, stream>>>(Gb, hf2, hf2, hb2);
  }
  // ---- decoder ----
  float* rel  = (float*)d_out;                         // (12, 2048, 5)
  float* pred = (float*)d_out + (size_t)12 * NB * 5;   // (12, 2048, 16)
  for (int k = 0; k < 12; ++k) {
    k_gates<<<gg, 256, 0, stream>>>(Edec, hb2, P3rz, P3in, P3hn, bias2, nullptr, Gb);
    k_gru<<<768, 256, 0, stream>>>(Gb, hf2, hf2, hb2);
    const float* o2 = (k == 0) ? observed + (size_t)7 * NB * DD
                               : pred + (size_t)(k - 1) * NB * DD;
    k_head<<<NB / 4, 256, 0, stream>>>(hf2, o2, h2n_W, h2n_b, mix_W, mix_b, emb_W, emb_b,
                                       rel + (size_t)k * NB * 5, pred + (size_t)k * NB * DD,
                                       Edec);
  }
}

// Round 3
// 865.087 us; speedup vs baseline: 1.7768x; 1.6078x over previous
//
#include <hip/hip_runtime.h>
#include <hip/hip_bf16.h>
#include <math.h>

#define H 768
#define NB 2048
#define DD 16
// packed gate matrix: 3072 cols = 48 tiles x (16 r | 16 z | 16 in | 16 hn), K = 800 = 768 h + 16 vel + 16 pad

typedef __attribute__((ext_vector_type(8))) short bf16x8;
typedef __attribute__((ext_vector_type(4))) float f32x4;

__device__ __forceinline__ void gload_lds16(const void* g, void* lds) {
  __builtin_amdgcn_global_load_lds((const __attribute__((address_space(1))) void*)g,
                                   (__attribute__((address_space(3))) void*)lds, 16, 0, 0);
}
__device__ __forceinline__ float b2f(short s) {
  union { unsigned int u; float f; } c;
  c.u = ((unsigned int)(unsigned short)s) << 16;
  return c.f;
}
__device__ __forceinline__ short f2bs(float f) {
  __hip_bfloat16 h = __float2bfloat16(f);
  return *(short*)&h;
}

// ---------- M1[s][g][d] = 4 * sum_e Wih_s[g][e] * emb_W[e][d] ----------
__global__ void k_m1(const float* __restrict__ e1W, const float* __restrict__ e2W,
                     const float* __restrict__ dW, const float* __restrict__ embW,
                     float* __restrict__ M1) {
  int idx = blockIdx.x * 256 + threadIdx.x;  // < 3*2304*16
  if (idx >= 3 * 2304 * 16) return;
  int d = idx & 15, g = (idx >> 4) % 2304, s = idx / (2304 * 16);
  const float* W = s == 0 ? e1W : s == 1 ? e2W : dW;
  int ld = s == 1 ? 1024 : 256;
  float sum = 0.f;
  for (int e = 0; e < 256; ++e) sum += W[(size_t)g * ld + e] * embW[e * 16 + d];
  M1[idx] = 4.0f * sum;
}

// ---------- packed bias [3][3072]: embeds emb_b fold ----------
__global__ void k_biasP(const float* __restrict__ e1W, const float* __restrict__ e2W,
                        const float* __restrict__ dW, const float* __restrict__ embB,
                        const float* b1i, const float* b1h, const float* b2i, const float* b2h,
                        const float* b3i, const float* b3h, float* __restrict__ out) {
  int idx = blockIdx.x * 256 + threadIdx.x;  // < 3*3072
  if (idx >= 3 * 3072) return;
  int c = idx % 3072, s = idx / 3072;
  int f = (c >> 4) & 3, u = (c >> 6) * 16 + (c & 15);
  const float* W = s == 0 ? e1W : s == 1 ? e2W : dW;
  int ld = s == 1 ? 1024 : 256;
  const float* bi = s == 0 ? b1i : s == 1 ? b2i : b3i;
  const float* bh = s == 0 ? b1h : s == 1 ? b2h : b3h;
  float v;
  if (f == 3) {
    v = bh[1536 + u];
  } else {
    int g = (f < 2 ? f * 768 : 1536) + u;
    float acc = bi[g] + (f < 2 ? bh[g] : 0.f);
    for (int e = 0; e < 256; ++e) acc += W[(size_t)g * ld + e] * embB[e];
    v = acc;
  }
  out[idx] = v;
}

// ---------- pack one weight set -> Bp[3072][800] bf16 ----------
__global__ void k_packB(const float* __restrict__ Whh, const float* __restrict__ M1s,
                        __hip_bfloat16* __restrict__ Bp) {
  int idx = blockIdx.x * 256 + threadIdx.x;  // < 3072*800
  if (idx >= 3072 * 800) return;
  int k = idx % 800, c = idx / 800;
  int f = (c >> 4) & 3, u = (c >> 6) * 16 + (c & 15);
  float v = 0.f;
  if (k < 768) {
    if (f == 0) v = Whh[(size_t)u * 768 + k];
    else if (f == 1) v = Whh[(size_t)(768 + u) * 768 + k];
    else if (f == 3) v = Whh[(size_t)(1536 + u) * 768 + k];
  } else if (k < 784) {
    if (f < 3) v = M1s[(size_t)(f * 768 + u) * 16 + (k - 768)];
  }
  Bp[idx] = __float2bfloat16(v);
}

// ---------- pack e2_Wih[:,256:] into interleaved order -> B2g[3072][768] ----------
__global__ void k_packB2g(const float* __restrict__ e2W, __hip_bfloat16* __restrict__ B2g) {
  int idx = blockIdx.x * 256 + threadIdx.x;  // < 3072*768
  if (idx >= 3072 * 768) return;
  int k = idx % 768, c = idx / 768;
  int f = (c >> 4) & 3, u = (c >> 6) * 16 + (c & 15);
  float v = (f < 3) ? e2W[(size_t)(f * 768 + u) * 1024 + 256 + k] : 0.f;
  B2g[idx] = __float2bfloat16(v);
}

// ---------- velocities for 7 frames, zero-padded to 32 ----------
__global__ void k_vel(const float* __restrict__ obs, __hip_bfloat16* __restrict__ velall) {
  int idx = blockIdx.x * 256 + threadIdx.x;  // < 7*2048*32
  if (idx >= 7 * 2048 * 32) return;
  int d = idx & 31, n = (idx >> 5) & 2047, s = idx >> 16;
  float v = 0.f;
  if (d < 16)
    v = obs[((size_t)(s + 1) * NB + n) * DD + d] - obs[((size_t)s * NB + n) * DD + d];
  velall[idx] = __float2bfloat16(v);
}

// ---------- plain GEMM for g2add: C[2048][N] = A(2048x768) @ B(N x 768)^T ----------
__global__ __launch_bounds__(256) void k_plain(
    const __hip_bfloat16* __restrict__ A, const __hip_bfloat16* __restrict__ B,
    __hip_bfloat16* __restrict__ C, int ldc) {
  __shared__ __align__(16) __hip_bfloat16 Asm[128 * 32];
  __shared__ __align__(16) __hip_bfloat16 Bsm[128 * 32];
  const int tid = threadIdx.x;
  const int w = tid >> 6, l = tid & 63;
  const int bm = blockIdx.y, bn = blockIdx.x;
  const int wm = w >> 1, wn = w & 1;
  const int lr = l & 15, lk = l >> 4;
  f32x4 acc[4][4];
#pragma unroll
  for (int m = 0; m < 4; ++m)
#pragma unroll
    for (int n = 0; n < 4; ++n) acc[m][n] = (f32x4){0.f, 0.f, 0.f, 0.f};
  const int rowA = bm * 128, rowB = bn * 128;
  const int off0 = w * 1024 + l * 16;
  for (int kb = 0; kb < H; kb += 32) {
#pragma unroll
    for (int i = 0; i < 2; ++i) {
      int o = i * 4096 + off0;
      int r = o >> 6, kk = (o & 63) >> 1;
      gload_lds16(A + (size_t)(rowA + r) * H + kb + kk, (char*)Asm + i * 4096 + w * 1024);
      gload_lds16(B + (size_t)(rowB + r) * H + kb + kk, (char*)Bsm + i * 4096 + w * 1024);
    }
    __syncthreads();
    bf16x8 af[4], bfr[4];
#pragma unroll
    for (int m = 0; m < 4; ++m)
      af[m] = *(const bf16x8*)(Asm + (wm * 64 + m * 16 + lr) * 32 + lk * 8);
#pragma unroll
    for (int n = 0; n < 4; ++n)
      bfr[n] = *(const bf16x8*)(Bsm + (wn * 64 + n * 16 + lr) * 32 + lk * 8);
#pragma unroll
    for (int m = 0; m < 4; ++m)
#pragma unroll
      for (int n = 0; n < 4; ++n)
        acc[m][n] = __builtin_amdgcn_mfma_f32_16x16x32_bf16(af[m], bfr[n], acc[m][n], 0, 0, 0);
    __syncthreads();
  }
#pragma unroll
  for (int m = 0; m < 4; ++m)
#pragma unroll
    for (int n = 0; n < 4; ++n) {
      int col = bn * 128 + wn * 64 + n * 16 + lr;
#pragma unroll
      for (int r4 = 0; r4 < 4; ++r4) {
        int row = rowA + wm * 64 + m * 16 + lk * 4 + r4;
        C[(size_t)row * ldc + col] = __float2bfloat16(acc[m][n][r4]);
      }
    }
}

// ---------- fused step: gates GEMM (K=800, interleaved cols) + GRU epilogue ----------
// grid (48, 16), 256 threads. 3-deep LDS ring, counted vmcnt, 1 barrier/iter.
__global__ __launch_bounds__(256) void k_step(
    const __hip_bfloat16* __restrict__ hin,  // 2048 x 768
    const __hip_bfloat16* __restrict__ vel,  // 2048 x 32
    const __hip_bfloat16* __restrict__ Bp,   // 3072 x 800
    const float* __restrict__ bias,          // 3072 packed
    const __hip_bfloat16* __restrict__ g2a,  // 2048 x 3072 interleaved or null
    __hip_bfloat16* __restrict__ hout) {     // 2048 x 768
  __shared__ __align__(16) char lds[36864];  // 3 bufs x (A 8KB + B 4KB); epilogue tile reuses
  const int tid = threadIdx.x;
  const int w = tid >> 6, l = tid & 63;
  const int nt = blockIdx.x, bm = blockIdx.y;
  const int rowA = bm * 128, colB = nt * 64;
  const int lr = l & 15, lk = l >> 4;
  const int wbase = w * 1024;
  const int ce = (tid & 3) * 8, rA = tid >> 2;

  auto STAGE = [&](int bufo, int kb) {
#pragma unroll
    for (int i_ = 0; i_ < 2; ++i_) {
      int r_ = i_ * 64 + rA;
      const __hip_bfloat16* s_ = (kb < 768)
          ? hin + (size_t)(rowA + r_) * H + kb + ce
          : vel + (size_t)(rowA + r_) * 32 + ce;
      gload_lds16(s_, lds + bufo + i_ * 4096 + wbase);
    }
    gload_lds16(Bp + (size_t)(colB + rA) * 800 + kb + ce, lds + bufo + 8192 + wbase);
  };

  f32x4 acc[2][4];
#pragma unroll
  for (int m = 0; m < 2; ++m)
#pragma unroll
    for (int n = 0; n < 4; ++n) acc[m][n] = (f32x4){0.f, 0.f, 0.f, 0.f};

  const int bo[3] = {0, 12288, 24576};
  STAGE(bo[0], 0);
  STAGE(bo[1], 32);

  for (int ki = 0; ki < 25; ++ki) {
    if (ki < 24) asm volatile("s_waitcnt vmcnt(3)" ::: "memory");
    else         asm volatile("s_waitcnt vmcnt(0)" ::: "memory");
    __builtin_amdgcn_sched_barrier(0);
    __builtin_amdgcn_s_barrier();
    __builtin_amdgcn_sched_barrier(0);
    if (ki < 23) STAGE(bo[(ki + 2) % 3], (ki + 2) * 32);
    const int cur = bo[ki % 3];
    const __hip_bfloat16* Ab = (const __hip_bfloat16*)(lds + cur);
    const __hip_bfloat16* Bb = (const __hip_bfloat16*)(lds + cur + 8192);
    bf16x8 a0 = *(const bf16x8*)(Ab + (w * 32 + lr) * 32 + lk * 8);
    bf16x8 a1 = *(const bf16x8*)(Ab + (w * 32 + 16 + lr) * 32 + lk * 8);
    bf16x8 b0 = *(const bf16x8*)(Bb + lr * 32 + lk * 8);
    bf16x8 b1 = *(const bf16x8*)(Bb + (16 + lr) * 32 + lk * 8);
    const bool last = (ki == 24);
    bf16x8 b2 = *(const bf16x8*)(Bb + ((last ? 32 : 48) + lr) * 32 + lk * 8);
    acc[0][0] = __builtin_amdgcn_mfma_f32_16x16x32_bf16(a0, b0, acc[0][0], 0, 0, 0);
    acc[1][0] = __builtin_amdgcn_mfma_f32_16x16x32_bf16(a1, b0, acc[1][0], 0, 0, 0);
    acc[0][1] = __builtin_amdgcn_mfma_f32_16x16x32_bf16(a0, b1, acc[0][1], 0, 0, 0);
    acc[1][1] = __builtin_amdgcn_mfma_f32_16x16x32_bf16(a1, b1, acc[1][1], 0, 0, 0);
    if (last) {
      acc[0][2] = __builtin_amdgcn_mfma_f32_16x16x32_bf16(a0, b2, acc[0][2], 0, 0, 0);
      acc[1][2] = __builtin_amdgcn_mfma_f32_16x16x32_bf16(a1, b2, acc[1][2], 0, 0, 0);
    } else {
      acc[0][3] = __builtin_amdgcn_mfma_f32_16x16x32_bf16(a0, b2, acc[0][3], 0, 0, 0);
      acc[1][3] = __builtin_amdgcn_mfma_f32_16x16x32_bf16(a1, b2, acc[1][3], 0, 0, 0);
    }
  }

  __syncthreads();
  // dump biased pre-activations to LDS tile [128][72] bf16 (pad vs bank aliasing)
  short* T = (short*)lds;
  const float* bp = bias + nt * 64;
#pragma unroll
  for (int n = 0; n < 4; ++n) {
    float bv = bp[n * 16 + lr];
#pragma unroll
    for (int m = 0; m < 2; ++m) {
      int rbase = w * 32 + m * 16 + lk * 4;
#pragma unroll
      for (int r4 = 0; r4 < 4; ++r4)
        T[(rbase + r4) * 72 + n * 16 + lr] = f2bs(acc[m][n][r4] + bv);
    }
  }
  __syncthreads();

  // GRU: 256 threads x 8 units = 128 rows x 16 units
  const int row = tid >> 1;
  const int ub = (tid & 1) * 8;
  const size_t grow = (size_t)(rowA + row);
  const short* Tp = T + row * 72;
  bf16x8 Lr = *(const bf16x8*)(Tp + ub);
  bf16x8 Lz = *(const bf16x8*)(Tp + 16 + ub);
  bf16x8 Li = *(const bf16x8*)(Tp + 32 + ub);
  bf16x8 Lh = *(const bf16x8*)(Tp + 48 + ub);
  bf16x8 h8 = *(const bf16x8*)(hin + grow * H + nt * 16 + ub);
  bf16x8 gr, gz, gi_;
  if (g2a) {
    const __hip_bfloat16* gp = g2a + grow * 3072 + nt * 64;
    gr  = *(const bf16x8*)(gp + ub);
    gz  = *(const bf16x8*)(gp + 16 + ub);
    gi_ = *(const bf16x8*)(gp + 32 + ub);
  }
  union { bf16x8 v; short s[8]; } ob;
#pragma unroll
  for (int e = 0; e < 8; ++e) {
    float xr = b2f(Lr[e]), xz = b2f(Lz[e]), xi = b2f(Li[e]), xh = b2f(Lh[e]);
    if (g2a) { xr += b2f(gr[e]); xz += b2f(gz[e]); xi += b2f(gi_[e]); }
    float r = 1.f / (1.f + expf(-xr));
    float z = 1.f / (1.f + expf(-xz));
    float nn = tanhf(xi + r * xh);
    float hv = (1.f - z) * nn + z * b2f(h8[e]);
    ob.s[e] = f2bs(hv);
  }
  *(bf16x8*)(hout + grow * H + nt * 16 + ub) = ob.v;
}

// ---------- decoder head: h2n + mix + pos + next-step velocity (bf16, padded) ----------
__global__ void k_head(const __hip_bfloat16* __restrict__ h, const float* __restrict__ obs2,
                       const float* __restrict__ h2n_W, const float* __restrict__ h2n_b,
                       const float* __restrict__ mix_W, const float* __restrict__ mix_b,
                       float* __restrict__ rel_out, float* __restrict__ pos_out,
                       __hip_bfloat16* __restrict__ velout) {
  int wv = threadIdx.x >> 6, lane = threadIdx.x & 63;
  int row = blockIdx.x * 4 + wv;
  float s0 = 0.f, s1 = 0.f, s2 = 0.f, s3 = 0.f, s4 = 0.f;
  for (int k = lane; k < H; k += 64) {
    float hv = b2f(((const short*)h)[(size_t)row * H + k]);
    s0 += hv * h2n_W[k];
    s1 += hv * h2n_W[H + k];
    s2 += hv * h2n_W[2 * H + k];
    s3 += hv * h2n_W[3 * H + k];
    s4 += hv * h2n_W[4 * H + k];
  }
#pragma unroll
  for (int off = 32; off; off >>= 1) {
    s0 += __shfl_down(s0, off);
    s1 += __shfl_down(s1, off);
    s2 += __shfl_down(s2, off);
    s3 += __shfl_down(s3, off);
    s4 += __shfl_down(s4, off);
  }
  s0 = __shfl(s0, 0); s1 = __shfl(s1, 0); s2 = __shfl(s2, 0);
  s3 = __shfl(s3, 0); s4 = __shfl(s4, 0);
  float n0 = s0 + h2n_b[0], n1 = s1 + h2n_b[1];
  float x2 = s2 + h2n_b[2], x3 = s3 + h2n_b[3], x4 = s4 + h2n_b[4];
  float n2 = 0.01f + 0.2f * (x2 > 0.f ? x2 + log1pf(expf(-x2)) : log1pf(expf(x2)));
  float n3 = 0.01f + 0.2f * (x3 > 0.f ? x3 + log1pf(expf(-x3)) : log1pf(expf(x3)));
  float n4 = 0.7f * tanhf(x4);
  float rl = 0.f;
  if (lane < DD) {
    float a = mix_b[lane] + n0 * mix_W[lane * 5 + 0] + n1 * mix_W[lane * 5 + 1] +
              n2 * mix_W[lane * 5 + 2] + n3 * mix_W[lane * 5 + 3] + n4 * mix_W[lane * 5 + 4];
    rl = a > 0.f ? a : 0.f;
    pos_out[(size_t)row * DD + lane] = obs2[(size_t)row * DD + lane] + rl;
  }
  if (lane < 32)
    velout[(size_t)row * 32 + lane] = __float2bfloat16(lane < DD ? rl : 0.f);
  if (lane == 0) {
    rel_out[(size_t)row * 5 + 0] = n0;
    rel_out[(size_t)row * 5 + 1] = n1;
    rel_out[(size_t)row * 5 + 2] = n2;
    rel_out[(size_t)row * 5 + 3] = n3;
    rel_out[(size_t)row * 5 + 4] = n4;
  }
}

extern "C" void kernel_launch(void* const* d_in, const int* in_sizes, int n_in,
                              void* d_out, int out_size, void* d_ws, size_t ws_size,
                              hipStream_t stream) {
  (void)in_sizes; (void)n_in; (void)out_size; (void)ws_size;
  const float* observed = (const float*)d_in[0];
  const float* emb_W   = (const float*)d_in[1];
  const float* emb_b   = (const float*)d_in[2];
  const float* e1_Wih  = (const float*)d_in[3];
  const float* e1_Whh  = (const float*)d_in[4];
  const float* e1_bih  = (const float*)d_in[5];
  const float* e1_bhh  = (const float*)d_in[6];
  const float* e2_Wih  = (const float*)d_in[7];
  const float* e2_Whh  = (const float*)d_in[8];
  const float* e2_bih  = (const float*)d_in[9];
  const float* e2_bhh  = (const float*)d_in[10];
  const float* dec_Wih = (const float*)d_in[11];
  const float* dec_Whh = (const float*)d_in[12];
  const float* dec_bih = (const float*)d_in[13];
  const float* dec_bhh = (const float*)d_in[14];
  const float* h2n_W   = (const float*)d_in[15];
  const float* h2n_b   = (const float*)d_in[16];
  const float* mix_W   = (const float*)d_in[17];
  const float* mix_b   = (const float*)d_in[18];

  char* p = (char*)d_ws;
  auto alloc = [&](size_t bytes) { char* r = p; p += (bytes + 255) & ~(size_t)255; return r; };

  __hip_bfloat16* hz     = (__hip_bfloat16*)alloc((size_t)NB * H * 2);
  __hip_bfloat16* hp0    = (__hip_bfloat16*)alloc((size_t)NB * H * 2);
  __hip_bfloat16* hp1    = (__hip_bfloat16*)alloc((size_t)NB * H * 2);
  __hip_bfloat16* velall = (__hip_bfloat16*)alloc((size_t)7 * NB * 32 * 2);
  __hip_bfloat16* dvel   = (__hip_bfloat16*)alloc((size_t)NB * 32 * 2);
  __hip_bfloat16* Bp1    = (__hip_bfloat16*)alloc((size_t)3072 * 800 * 2);
  __hip_bfloat16* Bp2    = (__hip_bfloat16*)alloc((size_t)3072 * 800 * 2);
  __hip_bfloat16* Bp3    = (__hip_bfloat16*)alloc((size_t)3072 * 800 * 2);
  __hip_bfloat16* B2g    = (__hip_bfloat16*)alloc((size_t)3072 * 768 * 2);
  __hip_bfloat16* g2add  = (__hip_bfloat16*)alloc((size_t)NB * 3072 * 2);
  float*          M1     = (float*)alloc((size_t)3 * 2304 * 16 * 4);
  float*          biasP  = (float*)alloc((size_t)3 * 3072 * 4);

  // ---- prep ----
  hipMemsetAsync(hz, 0, (size_t)NB * H * 2, stream);
  k_m1<<<(3 * 2304 * 16 + 255) / 256, 256, 0, stream>>>(e1_Wih, e2_Wih, dec_Wih, emb_W, M1);
  k_biasP<<<(3 * 3072 + 255) / 256, 256, 0, stream>>>(e1_Wih, e2_Wih, dec_Wih, emb_b,
                                                      e1_bih, e1_bhh, e2_bih, e2_bhh,
                                                      dec_bih, dec_bhh, biasP);
  k_packB<<<(3072 * 800 + 255) / 256, 256, 0, stream>>>(e1_Whh, M1, Bp1);
  k_packB<<<(3072 * 800 + 255) / 256, 256, 0, stream>>>(e2_Whh, M1 + 2304 * 16, Bp2);
  k_packB<<<(3072 * 800 + 255) / 256, 256, 0, stream>>>(dec_Whh, M1 + 2 * 2304 * 16, Bp3);
  k_packB2g<<<(3072 * 768 + 255) / 256, 256, 0, stream>>>(e2_Wih, B2g);
  k_vel<<<(7 * NB * 32 + 255) / 256, 256, 0, stream>>>(observed, velall);

  dim3 gs(48, 16);
  const __hip_bfloat16* src;
  __hip_bfloat16* dst = hp0;

  // ---- encoder 1: velocity frames 6,5,...,0 ----
  src = hz;
  for (int t = 0; t < 7; ++t) {
    k_step<<<gs, 256, 0, stream>>>(src, velall + (size_t)(6 - t) * NB * 32, Bp1, biasP,
                                   nullptr, dst);
    src = dst;
    dst = (dst == hp0) ? hp1 : hp0;
  }
  // src = h_inv (hp0). g2add = h_inv @ B2g^T, interleaved layout
  k_plain<<<dim3(24, 16), 256, 0, stream>>>(src, B2g, g2add, 3072);

  // ---- encoder 2: frames 0..6 (dst currently hp1) ----
  src = hz;
  for (int t = 0; t < 7; ++t) {
    k_step<<<gs, 256, 0, stream>>>(src, velall + (size_t)t * NB * 32, Bp2, biasP + 3072,
                                   g2add, dst);
    src = dst;
    dst = (dst == hp0) ? hp1 : hp0;
  }

  // ---- decoder ----
  float* rel  = (float*)d_out;                       // (12, 2048, 5)
  float* pred = (float*)d_out + (size_t)12 * NB * 5; // (12, 2048, 16)
  for (int k = 0; k < 12; ++k) {
    const __hip_bfloat16* vk = (k == 0) ? velall + (size_t)6 * NB * 32 : dvel;
    k_step<<<gs, 256, 0, stream>>>(src, vk, Bp3, biasP + 2 * 3072, nullptr, dst);
    const float* o2 = (k == 0) ? observed + (size_t)7 * NB * DD
                               : pred + (size_t)(k - 1) * NB * DD;
    k_head<<<NB / 4, 256, 0, stream>>>(dst, o2, h2n_W, h2n_b, mix_W, mix_b,
                                       rel + (size_t)k * NB * 5, pred + (size_t)k * NB * DD,
                                       dvel);
    src = dst;
    dst = (dst == hp0) ? hp1 : hp0;
  }
}

// Round 4
// 773.280 us; speedup vs baseline: 1.9878x; 1.1187x over previous
//
#include <hip/hip_runtime.h>
#include <hip/hip_bf16.h>
#include <math.h>

#define H 768
#define NB 2048
#define DD 16
// packed gate matrix: 3072 cols = 48 tiles x (16 r | 16 z | 16 in | 16 hn), K = 800 = 768 h + 16 vel + 16 pad

typedef __attribute__((ext_vector_type(8))) short bf16x8;
typedef __attribute__((ext_vector_type(4))) float f32x4;

__device__ __forceinline__ void gload_lds16(const void* g, void* lds) {
  __builtin_amdgcn_global_load_lds((const __attribute__((address_space(1))) void*)g,
                                   (__attribute__((address_space(3))) void*)lds, 16, 0, 0);
}
__device__ __forceinline__ float b2f(short s) {
  union { unsigned int u; float f; } c;
  c.u = ((unsigned int)(unsigned short)s) << 16;
  return c.f;
}
__device__ __forceinline__ short f2bs(float f) {
  __hip_bfloat16 h = __float2bfloat16(f);
  return *(short*)&h;
}

// ---------- M1[s][g][d] = 4 * sum_e Wih_s[g][e] * emb_W[e][d] ----------
__global__ void k_m1(const float* __restrict__ e1W, const float* __restrict__ e2W,
                     const float* __restrict__ dW, const float* __restrict__ embW,
                     float* __restrict__ M1) {
  int idx = blockIdx.x * 256 + threadIdx.x;  // < 3*2304*16
  if (idx >= 3 * 2304 * 16) return;
  int d = idx & 15, g = (idx >> 4) % 2304, s = idx / (2304 * 16);
  const float* W = s == 0 ? e1W : s == 1 ? e2W : dW;
  int ld = s == 1 ? 1024 : 256;
  float sum = 0.f;
  for (int e = 0; e < 256; ++e) sum += W[(size_t)g * ld + e] * embW[e * 16 + d];
  M1[idx] = 4.0f * sum;
}

// ---------- packed bias [3][3072]: embeds emb_b fold ----------
__global__ void k_biasP(const float* __restrict__ e1W, const float* __restrict__ e2W,
                        const float* __restrict__ dW, const float* __restrict__ embB,
                        const float* b1i, const float* b1h, const float* b2i, const float* b2h,
                        const float* b3i, const float* b3h, float* __restrict__ out) {
  int idx = blockIdx.x * 256 + threadIdx.x;  // < 3*3072
  if (idx >= 3 * 3072) return;
  int c = idx % 3072, s = idx / 3072;
  int f = (c >> 4) & 3, u = (c >> 6) * 16 + (c & 15);
  const float* W = s == 0 ? e1W : s == 1 ? e2W : dW;
  int ld = s == 1 ? 1024 : 256;
  const float* bi = s == 0 ? b1i : s == 1 ? b2i : b3i;
  const float* bh = s == 0 ? b1h : s == 1 ? b2h : b3h;
  float v;
  if (f == 3) {
    v = bh[1536 + u];
  } else {
    int g = (f < 2 ? f * 768 : 1536) + u;
    float acc = bi[g] + (f < 2 ? bh[g] : 0.f);
    for (int e = 0; e < 256; ++e) acc += W[(size_t)g * ld + e] * embB[e];
    v = acc;
  }
  out[idx] = v;
}

// ---------- pack 3 weight sets -> Bp[3072][800] bf16 (grid.y selects set) ----------
__global__ void k_packB3(const float* __restrict__ W1, const float* __restrict__ W2,
                         const float* __restrict__ W3, const float* __restrict__ M1all,
                         __hip_bfloat16* __restrict__ B1, __hip_bfloat16* __restrict__ B2,
                         __hip_bfloat16* __restrict__ B3) {
  int idx = blockIdx.x * 256 + threadIdx.x;  // < 3072*800
  if (idx >= 3072 * 800) return;
  int s = blockIdx.y;
  const float* Whh = s == 0 ? W1 : s == 1 ? W2 : W3;
  const float* M1s = M1all + (size_t)s * 2304 * 16;
  __hip_bfloat16* Bp = s == 0 ? B1 : s == 1 ? B2 : B3;
  int k = idx % 800, c = idx / 800;
  int f = (c >> 4) & 3, u = (c >> 6) * 16 + (c & 15);
  float v = 0.f;
  if (k < 768) {
    if (f == 0) v = Whh[(size_t)u * 768 + k];
    else if (f == 1) v = Whh[(size_t)(768 + u) * 768 + k];
    else if (f == 3) v = Whh[(size_t)(1536 + u) * 768 + k];
  } else if (k < 784) {
    if (f < 3) v = M1s[(size_t)(f * 768 + u) * 16 + (k - 768)];
  }
  Bp[idx] = __float2bfloat16(v);
}

// ---------- pack e2_Wih[:,256:] into interleaved order -> B2g[3072][768] ----------
__global__ void k_packB2g(const float* __restrict__ e2W, __hip_bfloat16* __restrict__ B2g) {
  int idx = blockIdx.x * 256 + threadIdx.x;  // < 3072*768
  if (idx >= 3072 * 768) return;
  int k = idx % 768, c = idx / 768;
  int f = (c >> 4) & 3, u = (c >> 6) * 16 + (c & 15);
  float v = (f < 3) ? e2W[(size_t)(f * 768 + u) * 1024 + 256 + k] : 0.f;
  B2g[idx] = __float2bfloat16(v);
}

// ---------- velocities for 7 frames, zero-padded to 32 ----------
__global__ void k_vel(const float* __restrict__ obs, __hip_bfloat16* __restrict__ velall) {
  int idx = blockIdx.x * 256 + threadIdx.x;  // < 7*2048*32
  if (idx >= 7 * 2048 * 32) return;
  int d = idx & 31, n = (idx >> 5) & 2047, s = idx >> 16;
  float v = 0.f;
  if (d < 16)
    v = obs[((size_t)(s + 1) * NB + n) * DD + d] - obs[((size_t)s * NB + n) * DD + d];
  velall[idx] = __float2bfloat16(v);
}

// ---------- plain GEMM for g2add: C[2048][N] = A(2048x768) @ B(N x 768)^T ----------
__global__ __launch_bounds__(256) void k_plain(
    const __hip_bfloat16* __restrict__ A, const __hip_bfloat16* __restrict__ B,
    __hip_bfloat16* __restrict__ C, int ldc) {
  __shared__ __align__(16) __hip_bfloat16 Asm[128 * 32];
  __shared__ __align__(16) __hip_bfloat16 Bsm[128 * 32];
  const int tid = threadIdx.x;
  const int w = tid >> 6, l = tid & 63;
  const int bm = blockIdx.y, bn = blockIdx.x;
  const int wm = w >> 1, wn = w & 1;
  const int lr = l & 15, lk = l >> 4;
  const int ks = (((tid & 3) ^ ((tid >> 3) & 3)) << 3);      // swizzled source octet
  const int lks = ((lk ^ ((lr >> 1) & 3)) << 3);             // swizzled read octet
  f32x4 acc[4][4];
#pragma unroll
  for (int m = 0; m < 4; ++m)
#pragma unroll
    for (int n = 0; n < 4; ++n) acc[m][n] = (f32x4){0.f, 0.f, 0.f, 0.f};
  const int rowA = bm * 128, rowB = bn * 128;
  const int rA = tid >> 2;
  for (int kb = 0; kb < H; kb += 32) {
#pragma unroll
    for (int i = 0; i < 2; ++i) {
      int r = i * 64 + rA;
      gload_lds16(A + (size_t)(rowA + r) * H + kb + ks, (char*)Asm + i * 4096 + w * 1024);
      gload_lds16(B + (size_t)(rowB + r) * H + kb + ks, (char*)Bsm + i * 4096 + w * 1024);
    }
    __syncthreads();
    bf16x8 af[4], bfr[4];
#pragma unroll
    for (int m = 0; m < 4; ++m)
      af[m] = *(const bf16x8*)(Asm + (wm * 64 + m * 16 + lr) * 32 + lks);
#pragma unroll
    for (int n = 0; n < 4; ++n)
      bfr[n] = *(const bf16x8*)(Bsm + (wn * 64 + n * 16 + lr) * 32 + lks);
#pragma unroll
    for (int m = 0; m < 4; ++m)
#pragma unroll
      for (int n = 0; n < 4; ++n)
        acc[m][n] = __builtin_amdgcn_mfma_f32_16x16x32_bf16(af[m], bfr[n], acc[m][n], 0, 0, 0);
    __syncthreads();
  }
#pragma unroll
  for (int m = 0; m < 4; ++m)
#pragma unroll
    for (int n = 0; n < 4; ++n) {
      int col = bn * 128 + wn * 64 + n * 16 + lr;
#pragma unroll
      for (int r4 = 0; r4 < 4; ++r4) {
        int row = rowA + wm * 64 + m * 16 + lk * 4 + r4;
        C[(size_t)row * ldc + col] = __float2bfloat16(acc[m][n][r4]);
      }
    }
}

// ---------- fused step: gates GEMM (K=800, interleaved cols) + GRU epilogue ----------
// grid (48, 16), 256 threads. 4-deep LDS ring, counted vmcnt(6), swizzled LDS, setprio.
__global__ __launch_bounds__(256) void k_step(
    const __hip_bfloat16* __restrict__ hin,  // 2048 x 768
    const __hip_bfloat16* __restrict__ vel,  // 2048 x 32
    const __hip_bfloat16* __restrict__ Bp,   // 3072 x 800
    const float* __restrict__ bias,          // 3072 packed
    const __hip_bfloat16* __restrict__ g2a,  // 2048 x 3072 interleaved or null
    __hip_bfloat16* __restrict__ hout) {     // 2048 x 768
  __shared__ __align__(16) char lds[49152];  // 4 bufs x (A 8KB + B 4KB); epilogue reuses
  const int tid = threadIdx.x;
  const int w = tid >> 6, l = tid & 63;
  const int nt = blockIdx.x, bm = blockIdx.y;
  const int rowA = bm * 128, colB = nt * 64;
  const int lr = l & 15, lk = l >> 4;
  const int wbase = w * 1024;
  const int rA = tid >> 2;
  const int ce = (((tid & 3) ^ ((tid >> 3) & 3)) << 3);   // swizzled source octet
  const int lks = ((lk ^ ((lr >> 1) & 3)) << 3);          // swizzled read octet

  auto STAGE = [&](int buf, int kb) {
#pragma unroll
    for (int i_ = 0; i_ < 2; ++i_) {
      int r_ = i_ * 64 + rA;
      const __hip_bfloat16* s_ = (kb < 768)
          ? hin + (size_t)(rowA + r_) * H + kb + ce
          : vel + (size_t)(rowA + r_) * 32 + ce;
      gload_lds16(s_, lds + buf * 12288 + i_ * 4096 + wbase);
    }
    gload_lds16(Bp + (size_t)(colB + rA) * 800 + kb + ce, lds + buf * 12288 + 8192 + wbase);
  };

  f32x4 acc[2][4];
#pragma unroll
  for (int m = 0; m < 2; ++m)
#pragma unroll
    for (int n = 0; n < 4; ++n) acc[m][n] = (f32x4){0.f, 0.f, 0.f, 0.f};

  STAGE(0, 0);
  STAGE(1, 32);
  STAGE(2, 64);

#pragma unroll
  for (int ki = 0; ki < 25; ++ki) {
    if (ki < 23)      asm volatile("s_waitcnt vmcnt(6)" ::: "memory");
    else if (ki == 23) asm volatile("s_waitcnt vmcnt(3)" ::: "memory");
    else               asm volatile("s_waitcnt vmcnt(0)" ::: "memory");
    __builtin_amdgcn_sched_barrier(0);
    __builtin_amdgcn_s_barrier();
    __builtin_amdgcn_sched_barrier(0);
    if (ki < 22) STAGE((ki + 3) & 3, (ki + 3) * 32);
    const char* cur = lds + (ki & 3) * 12288;
    const __hip_bfloat16* Ab = (const __hip_bfloat16*)cur;
    const __hip_bfloat16* Bb = (const __hip_bfloat16*)(cur + 8192);
    bf16x8 a0 = *(const bf16x8*)(Ab + (w * 32 + lr) * 32 + lks);
    bf16x8 a1 = *(const bf16x8*)(Ab + (w * 32 + 16 + lr) * 32 + lks);
    bf16x8 b0 = *(const bf16x8*)(Bb + lr * 32 + lks);
    bf16x8 b1 = *(const bf16x8*)(Bb + (16 + lr) * 32 + lks);
    const bool last = (ki == 24);
    bf16x8 b2 = *(const bf16x8*)(Bb + ((last ? 32 : 48) + lr) * 32 + lks);
    __builtin_amdgcn_s_setprio(1);
    acc[0][0] = __builtin_amdgcn_mfma_f32_16x16x32_bf16(a0, b0, acc[0][0], 0, 0, 0);
    acc[1][0] = __builtin_amdgcn_mfma_f32_16x16x32_bf16(a1, b0, acc[1][0], 0, 0, 0);
    acc[0][1] = __builtin_amdgcn_mfma_f32_16x16x32_bf16(a0, b1, acc[0][1], 0, 0, 0);
    acc[1][1] = __builtin_amdgcn_mfma_f32_16x16x32_bf16(a1, b1, acc[1][1], 0, 0, 0);
    if (last) {
      acc[0][2] = __builtin_amdgcn_mfma_f32_16x16x32_bf16(a0, b2, acc[0][2], 0, 0, 0);
      acc[1][2] = __builtin_amdgcn_mfma_f32_16x16x32_bf16(a1, b2, acc[1][2], 0, 0, 0);
    } else {
      acc[0][3] = __builtin_amdgcn_mfma_f32_16x16x32_bf16(a0, b2, acc[0][3], 0, 0, 0);
      acc[1][3] = __builtin_amdgcn_mfma_f32_16x16x32_bf16(a1, b2, acc[1][3], 0, 0, 0);
    }
    __builtin_amdgcn_s_setprio(0);
  }

  __syncthreads();
  // dump biased pre-activations to LDS tile [128][72] bf16
  short* T = (short*)lds;
  const float* bp = bias + nt * 64;
#pragma unroll
  for (int n = 0; n < 4; ++n) {
    float bv = bp[n * 16 + lr];
#pragma unroll
    for (int m = 0; m < 2; ++m) {
      int rbase = w * 32 + m * 16 + lk * 4;
#pragma unroll
      for (int r4 = 0; r4 < 4; ++r4)
        T[(rbase + r4) * 72 + n * 16 + lr] = f2bs(acc[m][n][r4] + bv);
    }
  }
  __syncthreads();

  // GRU: 256 threads x 8 units = 128 rows x 16 units
  const int row = tid >> 1;
  const int ub = (tid & 1) * 8;
  const size_t grow = (size_t)(rowA + row);
  const short* Tp = T + row * 72;
  bf16x8 Lr = *(const bf16x8*)(Tp + ub);
  bf16x8 Lz = *(const bf16x8*)(Tp + 16 + ub);
  bf16x8 Li = *(const bf16x8*)(Tp + 32 + ub);
  bf16x8 Lh = *(const bf16x8*)(Tp + 48 + ub);
  bf16x8 h8 = *(const bf16x8*)(hin + grow * H + nt * 16 + ub);
  bf16x8 gr, gz, gi_;
  if (g2a) {
    const __hip_bfloat16* gp = g2a + grow * 3072 + nt * 64;
    gr  = *(const bf16x8*)(gp + ub);
    gz  = *(const bf16x8*)(gp + 16 + ub);
    gi_ = *(const bf16x8*)(gp + 32 + ub);
  }
  union { bf16x8 v; short s[8]; } ob;
#pragma unroll
  for (int e = 0; e < 8; ++e) {
    float xr = b2f(Lr[e]), xz = b2f(Lz[e]), xi = b2f(Li[e]), xh = b2f(Lh[e]);
    if (g2a) { xr += b2f(gr[e]); xz += b2f(gz[e]); xi += b2f(gi_[e]); }
    float r = 1.f / (1.f + expf(-xr));
    float z = 1.f / (1.f + expf(-xz));
    float nn = tanhf(xi + r * xh);
    float hv = (1.f - z) * nn + z * b2f(h8[e]);
    ob.s[e] = f2bs(hv);
  }
  *(bf16x8*)(hout + grow * H + nt * 16 + ub) = ob.v;
}

// ---------- decoder head: h2n + mix + pos + next-step velocity (bf16, padded) ----------
__global__ void k_head(const __hip_bfloat16* __restrict__ h, const float* __restrict__ obs2,
                       const float* __restrict__ h2n_W, const float* __restrict__ h2n_b,
                       const float* __restrict__ mix_W, const float* __restrict__ mix_b,
                       float* __restrict__ rel_out, float* __restrict__ pos_out,
                       __hip_bfloat16* __restrict__ velout) {
  int wv = threadIdx.x >> 6, lane = threadIdx.x & 63;
  int row = blockIdx.x * 4 + wv;
  float s0 = 0.f, s1 = 0.f, s2 = 0.f, s3 = 0.f, s4 = 0.f;
  for (int k = lane; k < H; k += 64) {
    float hv = b2f(((const short*)h)[(size_t)row * H + k]);
    s0 += hv * h2n_W[k];
    s1 += hv * h2n_W[H + k];
    s2 += hv * h2n_W[2 * H + k];
    s3 += hv * h2n_W[3 * H + k];
    s4 += hv * h2n_W[4 * H + k];
  }
#pragma unroll
  for (int off = 32; off; off >>= 1) {
    s0 += __shfl_down(s0, off);
    s1 += __shfl_down(s1, off);
    s2 += __shfl_down(s2, off);
    s3 += __shfl_down(s3, off);
    s4 += __shfl_down(s4, off);
  }
  s0 = __shfl(s0, 0); s1 = __shfl(s1, 0); s2 = __shfl(s2, 0);
  s3 = __shfl(s3, 0); s4 = __shfl(s4, 0);
  float n0 = s0 + h2n_b[0], n1 = s1 + h2n_b[1];
  float x2 = s2 + h2n_b[2], x3 = s3 + h2n_b[3], x4 = s4 + h2n_b[4];
  float n2 = 0.01f + 0.2f * (x2 > 0.f ? x2 + log1pf(expf(-x2)) : log1pf(expf(x2)));
  float n3 = 0.01f + 0.2f * (x3 > 0.f ? x3 + log1pf(expf(-x3)) : log1pf(expf(x3)));
  float n4 = 0.7f * tanhf(x4);
  float rl = 0.f;
  if (lane < DD) {
    float a = mix_b[lane] + n0 * mix_W[lane * 5 + 0] + n1 * mix_W[lane * 5 + 1] +
              n2 * mix_W[lane * 5 + 2] + n3 * mix_W[lane * 5 + 3] + n4 * mix_W[lane * 5 + 4];
    rl = a > 0.f ? a : 0.f;
    pos_out[(size_t)row * DD + lane] = obs2[(size_t)row * DD + lane] + rl;
  }
  if (lane < 32)
    velout[(size_t)row * 32 + lane] = __float2bfloat16(lane < DD ? rl : 0.f);
  if (lane == 0) {
    rel_out[(size_t)row * 5 + 0] = n0;
    rel_out[(size_t)row * 5 + 1] = n1;
    rel_out[(size_t)row * 5 + 2] = n2;
    rel_out[(size_t)row * 5 + 3] = n3;
    rel_out[(size_t)row * 5 + 4] = n4;
  }
}

extern "C" void kernel_launch(void* const* d_in, const int* in_sizes, int n_in,
                              void* d_out, int out_size, void* d_ws, size_t ws_size,
                              hipStream_t stream) {
  (void)in_sizes; (void)n_in; (void)out_size; (void)ws_size;
  const float* observed = (const float*)d_in[0];
  const float* emb_W   = (const float*)d_in[1];
  const float* emb_b   = (const float*)d_in[2];
  const float* e1_Wih  = (const float*)d_in[3];
  const float* e1_Whh  = (const float*)d_in[4];
  const float* e1_bih  = (const float*)d_in[5];
  const float* e1_bhh  = (const float*)d_in[6];
  const float* e2_Wih  = (const float*)d_in[7];
  const float* e2_Whh  = (const float*)d_in[8];
  const float* e2_bih  = (const float*)d_in[9];
  const float* e2_bhh  = (const float*)d_in[10];
  const float* dec_Wih = (const float*)d_in[11];
  const float* dec_Whh = (const float*)d_in[12];
  const float* dec_bih = (const float*)d_in[13];
  const float* dec_bhh = (const float*)d_in[14];
  const float* h2n_W   = (const float*)d_in[15];
  const float* h2n_b   = (const float*)d_in[16];
  const float* mix_W   = (const float*)d_in[17];
  const float* mix_b   = (const float*)d_in[18];

  char* p = (char*)d_ws;
  auto alloc = [&](size_t bytes) { char* r = p; p += (bytes + 255) & ~(size_t)255; return r; };

  __hip_bfloat16* hz     = (__hip_bfloat16*)alloc((size_t)NB * H * 2);
  __hip_bfloat16* hp0    = (__hip_bfloat16*)alloc((size_t)NB * H * 2);
  __hip_bfloat16* hp1    = (__hip_bfloat16*)alloc((size_t)NB * H * 2);
  __hip_bfloat16* velall = (__hip_bfloat16*)alloc((size_t)7 * NB * 32 * 2);
  __hip_bfloat16* dvel   = (__hip_bfloat16*)alloc((size_t)NB * 32 * 2);
  __hip_bfloat16* Bp1    = (__hip_bfloat16*)alloc((size_t)3072 * 800 * 2);
  __hip_bfloat16* Bp2    = (__hip_bfloat16*)alloc((size_t)3072 * 800 * 2);
  __hip_bfloat16* Bp3    = (__hip_bfloat16*)alloc((size_t)3072 * 800 * 2);
  __hip_bfloat16* B2g    = (__hip_bfloat16*)alloc((size_t)3072 * 768 * 2);
  __hip_bfloat16* g2add  = (__hip_bfloat16*)alloc((size_t)NB * 3072 * 2);
  float*          M1     = (float*)alloc((size_t)3 * 2304 * 16 * 4);
  float*          biasP  = (float*)alloc((size_t)3 * 3072 * 4);

  // ---- prep ----
  hipMemsetAsync(hz, 0, (size_t)NB * H * 2, stream);
  k_m1<<<(3 * 2304 * 16 + 255) / 256, 256, 0, stream>>>(e1_Wih, e2_Wih, dec_Wih, emb_W, M1);
  k_biasP<<<(3 * 3072 + 255) / 256, 256, 0, stream>>>(e1_Wih, e2_Wih, dec_Wih, emb_b,
                                                      e1_bih, e1_bhh, e2_bih, e2_bhh,
                                                      dec_bih, dec_bhh, biasP);
  k_packB3<<<dim3((3072 * 800 + 255) / 256, 3), 256, 0, stream>>>(e1_Whh, e2_Whh, dec_Whh,
                                                                  M1, Bp1, Bp2, Bp3);
  k_packB2g<<<(3072 * 768 + 255) / 256, 256, 0, stream>>>(e2_Wih, B2g);
  k_vel<<<(7 * NB * 32 + 255) / 256, 256, 0, stream>>>(observed, velall);

  dim3 gs(48, 16);
  const __hip_bfloat16* src;
  __hip_bfloat16* dst = hp0;

  // ---- encoder 1: velocity frames 6,5,...,0 ----
  src = hz;
  for (int t = 0; t < 7; ++t) {
    k_step<<<gs, 256, 0, stream>>>(src, velall + (size_t)(6 - t) * NB * 32, Bp1, biasP,
                                   nullptr, dst);
    src = dst;
    dst = (dst == hp0) ? hp1 : hp0;
  }
  // src = h_inv. g2add = h_inv @ B2g^T, interleaved layout
  k_plain<<<dim3(24, 16), 256, 0, stream>>>(src, B2g, g2add, 3072);

  // ---- encoder 2: frames 0..6 ----
  src = hz;
  for (int t = 0; t < 7; ++t) {
    k_step<<<gs, 256, 0, stream>>>(src, velall + (size_t)t * NB * 32, Bp2, biasP + 3072,
                                   g2add, dst);
    src = dst;
    dst = (dst == hp0) ? hp1 : hp0;
  }

  // ---- decoder ----
  float* rel  = (float*)d_out;                       // (12, 2048, 5)
  float* pred = (float*)d_out + (size_t)12 * NB * 5; // (12, 2048, 16)
  for (int k = 0; k < 12; ++k) {
    const __hip_bfloat16* vk = (k == 0) ? velall + (size_t)6 * NB * 32 : dvel;
    k_step<<<gs, 256, 0, stream>>>(src, vk, Bp3, biasP + 2 * 3072, nullptr, dst);
    const float* o2 = (k == 0) ? observed + (size_t)7 * NB * DD
                               : pred + (size_t)(k - 1) * NB * DD;
    k_head<<<NB / 4, 256, 0, stream>>>(dst, o2, h2n_W, h2n_b, mix_W, mix_b,
                                       rel + (size_t)k * NB * 5, pred + (size_t)k * NB * DD,
                                       dvel);
    src = dst;
    dst = (dst == hp0) ? hp1 : hp0;
  }
}